// Round 12
// baseline (221.053 us; speedup 1.0000x reference)
//
#include <hip/hip_runtime.h>

// GAT_gate: B=16, N=1024, D=128. FP32 I/O; bf16 MFMA internally, fp32 accum.
//
// Round-12 (final config): round-9 k2_scores restored (best measured per-kernel:
// 45.6us, VGPR 84, no LDS stage -- r11's LDS-staged variant cut WRITE_SIZE
// 65->44MB but cost +30us in VGPR/LDS/conflict overhead). Totals across three
// structurally different configs (r9/r10-mega/r11) all land 221-225us: the
// timed metric is dominated by a fixed harness floor (~100us: input restore,
// ws re-poison, graph machinery) + ~125us kernel sum + +-4us noise.
//
//  K0:    WwB = bf16(Ww); W2T = bf16(A^T Ww); wbA = Wb@A (fp32)
//  kmask: adj (64MB fp32) -> 2MB bitmask (standalone wide grid -- r8 lesson:
//         ballot fused into a compute kernel serializes loads, 60us vs 14us)
//  K1:    h = x@Ww^T+Wb ; u = x@W2T^T+wbA -> h,u bf16; hT bf16 [b][d][n]
//  K2s:   grid 512: block = 32 rows i x all j; 16 A-frags hoisted; 4 indep
//         MFMA chains/tile; att = mask?exp(e):0 bf16 (32MB); partial colsums.
//  K2b:   rl0[j] = 1 / sum_iblk colpart
//  K3g:   pure GEMM h' = relu((att*rl0[j]) @ h) vs hT + LSTM-gate epilogue.

#define B_ 16
#define N_ 1024
#define D_ 128

typedef __attribute__((ext_vector_type(8))) short bf16x8;
typedef __attribute__((ext_vector_type(4))) float f32x4;

__device__ __forceinline__ float b2f(unsigned short u) {
    union { unsigned int i; float f; } v; v.i = ((unsigned int)u) << 16; return v.f;
}
__device__ __forceinline__ unsigned short f2b(float f) {
    union { float f; unsigned int i; } v; v.f = f;
    unsigned int x = v.i;
    return (unsigned short)((x + 0x7fffu + ((x >> 16) & 1u)) >> 16);
}
__device__ __forceinline__ float clamp60(float v) {
    return fminf(fmaxf(v, -60.f), 60.f);
}
__device__ __forceinline__ bf16x8 load8f(const float* p) {
    float4 a = *reinterpret_cast<const float4*>(p);
    float4 b = *reinterpret_cast<const float4*>(p + 4);
    bf16x8 v;
    v[0] = (short)f2b(a.x); v[1] = (short)f2b(a.y);
    v[2] = (short)f2b(a.z); v[3] = (short)f2b(a.w);
    v[4] = (short)f2b(b.x); v[5] = (short)f2b(b.y);
    v[6] = (short)f2b(b.z); v[7] = (short)f2b(b.w);
    return v;
}

// ---------------- K0: fold weights ----------------
__global__ __launch_bounds__(256) void k0_w2t(
    const float* __restrict__ Ww, const float* __restrict__ Wb,
    const float* __restrict__ A, unsigned short* __restrict__ WwB,
    unsigned short* __restrict__ W2T, float* __restrict__ wbA) {
    int t = blockIdx.x * 256 + threadIdx.x;
    int l = t >> 7, f = t & 127;
    float acc = 0.f;
    for (int d = 0; d < 128; ++d)
        acc += A[d * 128 + l] * Ww[d * 128 + f];
    W2T[l * 128 + f] = f2b(acc);
    WwB[t] = f2b(Ww[t]);
    if (blockIdx.x == 0 && threadIdx.x < 128) {
        float s = 0.f;
        for (int d = 0; d < 128; ++d) s += Wb[d] * A[d * 128 + threadIdx.x];
        wbA[threadIdx.x] = s;
    }
}

// ---------------- kmask: adj -> bitmask ----------------
__global__ __launch_bounds__(256) void kmask(
    const float* __restrict__ adj, unsigned long long* __restrict__ maskJ) {
    int w = threadIdx.x >> 6, lane = threadIdx.x & 63;
    size_t base = ((size_t)blockIdx.x * 4 + w) * 256;
    unsigned long long w0 = __ballot(adj[base + 0 * 64 + lane] > 0.f);
    unsigned long long w1 = __ballot(adj[base + 1 * 64 + lane] > 0.f);
    unsigned long long w2 = __ballot(adj[base + 2 * 64 + lane] > 0.f);
    unsigned long long w3 = __ballot(adj[base + 3 * 64 + lane] > 0.f);
    unsigned long long o = lane == 0 ? w0 : lane == 1 ? w1 : lane == 2 ? w2 : w3;
    if (lane < 4) maskJ[(base >> 6) + lane] = o;
}

// ---------------- K1: h, u, hT ----------------
__global__ __launch_bounds__(256) void k1_hu(
    const float* __restrict__ x, const unsigned short* __restrict__ WwB,
    const float* __restrict__ Wb, const unsigned short* __restrict__ W2T,
    const float* __restrict__ wbA,
    unsigned short* __restrict__ h, unsigned short* __restrict__ u,
    unsigned short* __restrict__ hT) {
    __shared__ unsigned short lds[16][128];
    int w = threadIdx.x >> 6, lane = threadIdx.x & 63;
    int c = lane & 15, q = lane >> 4;
    int rowbase = blockIdx.x * 16;
    int b = rowbase >> 10;
    int n0 = rowbase & 1023;
    bf16x8 xa[4];
    const float* xrow = x + (size_t)(rowbase + c) * 128;
#pragma unroll
    for (int ks = 0; ks < 4; ++ks)
        xa[ks] = load8f(xrow + ks * 32 + q * 8);
#pragma unroll
    for (int tt = 0; tt < 2; ++tt) {
        int t = w * 2 + tt;
        f32x4 acch = {0.f, 0.f, 0.f, 0.f};
        f32x4 accu = {0.f, 0.f, 0.f, 0.f};
        const unsigned short* wwrow = WwB + (t * 16 + c) * 128;
        const unsigned short* w2row = W2T + (t * 16 + c) * 128;
#pragma unroll
        for (int ks = 0; ks < 4; ++ks) {
            bf16x8 bw = *reinterpret_cast<const bf16x8*>(wwrow + ks * 32 + q * 8);
            bf16x8 b2 = *reinterpret_cast<const bf16x8*>(w2row + ks * 32 + q * 8);
            acch = __builtin_amdgcn_mfma_f32_16x16x32_bf16(xa[ks], bw, acch, 0, 0, 0);
            accu = __builtin_amdgcn_mfma_f32_16x16x32_bf16(xa[ks], b2, accu, 0, 0, 0);
        }
        float wb = Wb[t * 16 + c];
        float ub = wbA[t * 16 + c];
#pragma unroll
        for (int r = 0; r < 4; ++r) {
            int row = rowbase + q * 4 + r;
            unsigned short hv = f2b(acch[r] + wb);
            unsigned short uv = f2b(accu[r] + ub);
            h[(size_t)row * 128 + t * 16 + c] = hv;
            u[(size_t)row * 128 + t * 16 + c] = uv;
            lds[q * 4 + r][t * 16 + c] = hv;
        }
    }
    __syncthreads();
    int tid = threadIdx.x;
    if (tid < 128) {
        int d = tid;
        unsigned int p[8];
#pragma unroll
        for (int k = 0; k < 8; ++k) {
            unsigned int v0 = lds[2 * k][d], v1 = lds[2 * k + 1][d];
            p[k] = v0 | (v1 << 16);
        }
        size_t basehT = ((size_t)(b * 128 + d)) * 1024 + n0;
        uint4* dst = reinterpret_cast<uint4*>(hT + basehT);
        dst[0] = make_uint4(p[0], p[1], p[2], p[3]);
        dst[1] = make_uint4(p[4], p[5], p[6], p[7]);
    }
}

// K2s: grid 512: block = 32 rows i, all 1024 j. 4 MFMA chains per tile.
// (round-9 variant: best measured 45.6us)
__global__ __launch_bounds__(256) void k2_scores(
    const unsigned short* __restrict__ h, const unsigned short* __restrict__ u,
    const unsigned long long* __restrict__ maskJ,
    unsigned short* __restrict__ att, float* __restrict__ colpart) {
    __shared__ unsigned long long lmask[32][16];
    int w = threadIdx.x >> 6, lane = threadIdx.x & 63;
    int c = lane & 15, q = lane >> 4;
    int b = blockIdx.x >> 5;
    int iblk = blockIdx.x & 31;
    int i0 = iblk * 32;
    const unsigned short* hb = h + (size_t)b * N_ * D_;
    const unsigned short* ub = u + (size_t)b * N_ * D_;

    {
        int tid = threadIdx.x;
        lmask[tid >> 4][tid & 15] =
            maskJ[(size_t)(b * 1024 + i0 + (tid >> 4)) * 16 + (tid & 15)];
        lmask[16 + (tid >> 4)][tid & 15] =
            maskJ[(size_t)(b * 1024 + i0 + 16 + (tid >> 4)) * 16 + (tid & 15)];
    }
    __syncthreads();

    bf16x8 Au0[4], Ah0[4], Au1[4], Ah1[4];
#pragma unroll
    for (int ks = 0; ks < 4; ++ks) {
        Au0[ks] = *reinterpret_cast<const bf16x8*>(ub + (i0 + c) * 128 + ks * 32 + q * 8);
        Ah0[ks] = *reinterpret_cast<const bf16x8*>(hb + (i0 + c) * 128 + ks * 32 + q * 8);
        Au1[ks] = *reinterpret_cast<const bf16x8*>(ub + (i0 + 16 + c) * 128 + ks * 32 + q * 8);
        Ah1[ks] = *reinterpret_cast<const bf16x8*>(hb + (i0 + 16 + c) * 128 + ks * 32 + q * 8);
    }
    unsigned short* attrow = att + ((size_t)(b * 1024 + i0)) * 1024;
    float* cprow = colpart + ((size_t)(b * 32 + iblk)) * 1024;

    int jt0 = w * 16;                          // wave w: tiles jt0..jt0+15
#pragma unroll
    for (int t = 0; t < 16; ++t) {
        int jt = jt0 + t, j0 = jt * 16;
        bf16x8 Bh[4], Bu[4];
#pragma unroll
        for (int ks = 0; ks < 4; ++ks) {
            Bh[ks] = *reinterpret_cast<const bf16x8*>(hb + (j0 + c) * 128 + ks * 32 + q * 8);
            Bu[ks] = *reinterpret_cast<const bf16x8*>(ub + (j0 + c) * 128 + ks * 32 + q * 8);
        }
        f32x4 a00 = {0.f, 0.f, 0.f, 0.f};
        f32x4 a01 = {0.f, 0.f, 0.f, 0.f};
        f32x4 a10 = {0.f, 0.f, 0.f, 0.f};
        f32x4 a11 = {0.f, 0.f, 0.f, 0.f};
#pragma unroll
        for (int ks = 0; ks < 4; ++ks) {
            a00 = __builtin_amdgcn_mfma_f32_16x16x32_bf16(Au0[ks], Bh[ks], a00, 0, 0, 0);
            a01 = __builtin_amdgcn_mfma_f32_16x16x32_bf16(Ah0[ks], Bu[ks], a01, 0, 0, 0);
            a10 = __builtin_amdgcn_mfma_f32_16x16x32_bf16(Au1[ks], Bh[ks], a10, 0, 0, 0);
            a11 = __builtin_amdgcn_mfma_f32_16x16x32_bf16(Ah1[ks], Bu[ks], a11, 0, 0, 0);
        }
        int wd = jt >> 2, sh = (jt & 3) * 16;
        float colp = 0.f;
#pragma unroll
        for (int r = 0; r < 4; ++r) {
            float e0 = a00[r] + a01[r];         // e[i0+q*4+r][j0+c]
            float e1 = a10[r] + a11[r];         // e[i0+16+q*4+r][j0+c]
            bool m0 = (lmask[q * 4 + r][wd] >> (sh + c)) & 1ull;
            bool m1 = (lmask[16 + q * 4 + r][wd] >> (sh + c)) & 1ull;
            float ex0 = m0 ? __expf(clamp60(e0)) : 0.f;
            float ex1 = m1 ? __expf(clamp60(e1)) : 0.f;
            colp += (m0 ? ex0 : 1.0f) + (m1 ? ex1 : 1.0f);
            attrow[(size_t)(q * 4 + r) * 1024 + j0 + c] = f2b(ex0);
            attrow[(size_t)(16 + q * 4 + r) * 1024 + j0 + c] = f2b(ex1);
        }
        colp += __shfl_xor(colp, 16, 64);
        colp += __shfl_xor(colp, 32, 64);
        if (q == 0) cprow[j0 + c] = colp;
    }
}

// K2b: rl0 = 1/sum(colpart)
__global__ __launch_bounds__(256) void k2b_recip(
    const float* __restrict__ colpart, float* __restrict__ rl0) {
    int g = blockIdx.x * 256 + threadIdx.x;
    int b = g >> 10, j = g & 1023;
    float s = 0.f;
    const float* p = colpart + (size_t)b * 32 * 1024 + j;
    for (int ib = 0; ib < 32; ++ib) s += p[(size_t)ib * 1024];
    rl0[g] = 1.0f / s;
}

// K3g: pure GEMM h' = relu((att*rl0) @ h) + gates. att is bf16.
__global__ __launch_bounds__(256) void k3_gemm(
    const unsigned short* __restrict__ att, const float* __restrict__ rl0,
    const unsigned short* __restrict__ hT, const float* __restrict__ x,
    const float* __restrict__ wi_u, const float* __restrict__ wi_x,
    const float* __restrict__ wf_u, const float* __restrict__ wf_x,
    const float* __restrict__ wo_u, const float* __restrict__ wo_x,
    float* __restrict__ out) {
    __shared__ float red[4][16][129];
    int w = threadIdx.x >> 6, lane = threadIdx.x & 63;
    int c = lane & 15, q = lane >> 4;
    int b = blockIdx.x >> 6;
    int i0 = (blockIdx.x & 63) * 16;
    const unsigned short* attrow = att + ((size_t)(b * 1024 + i0 + c)) * 1024;
    const unsigned short* hTb = hT + (size_t)b * 128 * 1024;
    const float* rl0b = rl0 + b * 1024;
    f32x4 hp[8];
#pragma unroll
    for (int t = 0; t < 8; ++t) hp[t] = (f32x4){0.f, 0.f, 0.f, 0.f};
#pragma unroll
    for (int tt = 0; tt < 8; ++tt) {
        int jp = w * 8 + tt;
        int jb = jp * 32 + q * 8;
        bf16x8 eraw = *reinterpret_cast<const bf16x8*>(attrow + jb);
        float4 r0 = *reinterpret_cast<const float4*>(rl0b + jb);
        float4 r1 = *reinterpret_cast<const float4*>(rl0b + jb + 4);
        bf16x8 av;
        av[0] = (short)f2b(b2f((unsigned short)eraw[0]) * r0.x);
        av[1] = (short)f2b(b2f((unsigned short)eraw[1]) * r0.y);
        av[2] = (short)f2b(b2f((unsigned short)eraw[2]) * r0.z);
        av[3] = (short)f2b(b2f((unsigned short)eraw[3]) * r0.w);
        av[4] = (short)f2b(b2f((unsigned short)eraw[4]) * r1.x);
        av[5] = (short)f2b(b2f((unsigned short)eraw[5]) * r1.y);
        av[6] = (short)f2b(b2f((unsigned short)eraw[6]) * r1.z);
        av[7] = (short)f2b(b2f((unsigned short)eraw[7]) * r1.w);
#pragma unroll
        for (int t = 0; t < 8; ++t) {
            bf16x8 bt = *reinterpret_cast<const bf16x8*>(
                hTb + (size_t)(t * 16 + c) * 1024 + jp * 32 + q * 8);
            hp[t] = __builtin_amdgcn_mfma_f32_16x16x32_bf16(av, bt, hp[t], 0, 0, 0);
        }
    }
#pragma unroll
    for (int t = 0; t < 8; ++t)
#pragma unroll
        for (int r = 0; r < 4; ++r)
            red[w][q * 4 + r][t * 16 + c] = hp[t][r];
    __syncthreads();
    if (w != 0) return;
#pragma unroll
    for (int t = 0; t < 8; ++t)
#pragma unroll
        for (int r = 0; r < 4; ++r)
            hp[t][r] = red[0][q * 4 + r][t * 16 + c] + red[1][q * 4 + r][t * 16 + c]
                     + red[2][q * 4 + r][t * 16 + c] + red[3][q * 4 + r][t * 16 + c];
    float xv[8][4];
#pragma unroll
    for (int t = 0; t < 8; ++t)
#pragma unroll
        for (int r = 0; r < 4; ++r) {
            hp[t][r] = fmaxf(hp[t][r], 0.f);
            xv[t][r] = x[(size_t)(b * 1024 + i0 + q * 4 + r) * 128 + t * 16 + c];
        }
    float wiu[8], wix[8], wfu[8], wfx[8], wou[8], wox[8];
#pragma unroll
    for (int t = 0; t < 8; ++t) {
        wiu[t] = wi_u[t * 16 + c]; wix[t] = wi_x[t * 16 + c];
        wfu[t] = wf_u[t * 16 + c]; wfx[t] = wf_x[t * 16 + c];
        wou[t] = wo_u[t * 16 + c]; wox[t] = wo_x[t * 16 + c];
    }
#pragma unroll
    for (int r = 0; r < 4; ++r) {
        float zi = 0.f, zf = 0.f, zo = 0.f;
#pragma unroll
        for (int t = 0; t < 8; ++t) {
            zi += hp[t][r] * wiu[t] + xv[t][r] * wix[t];
            zf += hp[t][r] * wfu[t] + xv[t][r] * wfx[t];
            zo += hp[t][r] * wou[t] + xv[t][r] * wox[t];
        }
        zi += __shfl_xor(zi, 1, 64); zi += __shfl_xor(zi, 2, 64);
        zi += __shfl_xor(zi, 4, 64); zi += __shfl_xor(zi, 8, 64);
        zf += __shfl_xor(zf, 1, 64); zf += __shfl_xor(zf, 2, 64);
        zf += __shfl_xor(zf, 4, 64); zf += __shfl_xor(zf, 8, 64);
        zo += __shfl_xor(zo, 1, 64); zo += __shfl_xor(zo, 2, 64);
        zo += __shfl_xor(zo, 4, 64); zo += __shfl_xor(zo, 8, 64);
        float ic = 1.f / (1.f + __expf(-zi));
        float fc = 1.f / (1.f + __expf(-zf));
        float oc = 1.f / (1.f + __expf(-zo));
#pragma unroll
        for (int t = 0; t < 8; ++t) {
            float zz = ic * hp[t][r] + fc * xv[t][r];
            float th = 1.f - 2.f / (__expf(2.f * zz) + 1.f);
            out[(size_t)(b * 1024 + i0 + q * 4 + r) * 128 + t * 16 + c] = oc * th;
        }
    }
}

extern "C" void kernel_launch(void* const* d_in, const int* in_sizes, int n_in,
                              void* d_out, int out_size, void* d_ws, size_t ws_size,
                              hipStream_t stream) {
    const float* x    = (const float*)d_in[0];
    const float* adj  = (const float*)d_in[1];
    const float* Ww   = (const float*)d_in[2];
    const float* Wb   = (const float*)d_in[3];
    const float* A    = (const float*)d_in[4];
    const float* wi_u = (const float*)d_in[5];
    const float* wi_x = (const float*)d_in[6];
    const float* wf_u = (const float*)d_in[7];
    const float* wf_x = (const float*)d_in[8];
    const float* wo_u = (const float*)d_in[9];
    const float* wo_x = (const float*)d_in[10];
    float* out = (float*)d_out;
    char* ws = (char*)d_ws;

    if (ws_size >= (56ull << 20)) {
        unsigned short* WwB = (unsigned short*)(ws);                      // 32K
        unsigned short* W2T = (unsigned short*)(ws + (32u << 10));        // 32K
        float* wbA          = (float*)(ws + (64u << 10));                 // 512B
        float* rl0          = (float*)(ws + (128u << 10));                // 64K
        unsigned long long* maskJ = (unsigned long long*)(ws + (256u << 10)); // 2M
        float* colpart      = (float*)(ws + (4ull << 20));                // 2M
        unsigned short* h   = (unsigned short*)(ws + (8ull << 20));       // 4M
        unsigned short* u   = (unsigned short*)(ws + (12ull << 20));      // 4M
        unsigned short* hT  = (unsigned short*)(ws + (16ull << 20));      // 4M
        unsigned short* att = (unsigned short*)(ws + (20ull << 20));      // 32M

        k0_w2t<<<64, 256, 0, stream>>>(Ww, Wb, A, WwB, W2T, wbA);
        kmask<<<16384, 256, 0, stream>>>(adj, maskJ);
        k1_hu<<<1024, 256, 0, stream>>>(x, WwB, Wb, W2T, wbA, h, u, hT);
        k2_scores<<<512, 256, 0, stream>>>(h, u, maskJ, att, colpart);
        k2b_recip<<<64, 256, 0, stream>>>(colpart, rl0);
        k3_gemm<<<1024, 256, 0, stream>>>(att, rl0, hT, x,
                                          wi_u, wi_x, wf_u, wf_x, wo_u, wo_x, out);
    } else {
        // tighter layout (~49MB): same kernels
        unsigned short* WwB = (unsigned short*)(ws);
        unsigned short* W2T = (unsigned short*)(ws + (32u << 10));
        float* wbA          = (float*)(ws + (64u << 10));
        float* rl0          = (float*)(ws + (128u << 10));
        unsigned long long* maskJ = (unsigned long long*)(ws + (256u << 10));
        float* colpart      = (float*)(ws + (3ull << 20));
        unsigned short* h   = (unsigned short*)(ws + (5ull << 20));
        unsigned short* u   = (unsigned short*)(ws + (9ull << 20));
        unsigned short* hT  = (unsigned short*)(ws + (13ull << 20));
        unsigned short* att = (unsigned short*)(ws + (17ull << 20));

        k0_w2t<<<64, 256, 0, stream>>>(Ww, Wb, A, WwB, W2T, wbA);
        kmask<<<16384, 256, 0, stream>>>(adj, maskJ);
        k1_hu<<<1024, 256, 0, stream>>>(x, WwB, Wb, W2T, wbA, h, u, hT);
        k2_scores<<<512, 256, 0, stream>>>(h, u, maskJ, att, colpart);
        k2b_recip<<<64, 256, 0, stream>>>(colpart, rl0);
        k3_gemm<<<1024, 256, 0, stream>>>(att, rl0, hT, x,
                                          wi_u, wi_x, wf_u, wf_x, wo_u, wo_x, out);
    }
}